// Round 11
// baseline (467.159 us; speedup 1.0000x reference)
//
#include <hip/hip_runtime.h>

typedef unsigned short u16;
typedef unsigned int u32;

typedef __bf16 bf16x8 __attribute__((ext_vector_type(8)));
typedef float f32x4 __attribute__((ext_vector_type(4)));

union V16 { uint4 u; bf16x8 v; u16 s[8]; __bf16 h[8]; };
union F4  { float4 v; float f[4]; };

__device__ __forceinline__ float bf2f(u16 a) {
  union { u32 u; float f; } c; c.u = ((u32)a) << 16; return c.f;
}

#define Z_OFF   131072
#define ZM_OFF  147456
#define ZLV_OFF 163840

// ws layout in uint4 units (R0 layout, verbatim).
#define B1_OFF 0        // gen1_w: t<20, s<2
#define B2_OFF 2560     // gen2_w: t<20, s<10
#define E1_OFF 15360    // enc1_w: t<20, s<16
#define E2_OFF 35840    // enc2_w: t<20, s<10
#define ZMP_OFF 48640   // zm_w: t<4, s<10
#define ZVP_OFF 51200   // zv_w: t<4, s<10
#define FRAG_TOTAL 53760
#define WB4  53760      // W bf16 [512][64]     : 4096 uint4
#define XB4  57856      // x bf16 [256][512]    : 16384 uint4
#define H1_4 74240      // h1 bf16 [256][320]   : 10240 uint4
#define H2_4 84480      // h2 bf16 [256][320]   : 10240 uint4
#define PACK_THREADS (FRAG_TOTAL + 4096 + 16384)   // 74240

__device__ __forceinline__ void pack_one(const float* __restrict__ src,
                                         int t, int s, int lane,
                                         int Nsrc, int Ksrc, int rowlen,
                                         uint4* __restrict__ dst) {
  const int n = t * 16 + (lane & 15);
  const int k0 = s * 32 + ((lane >> 4) << 3);
  V16 v;
#pragma unroll
  for (int j = 0; j < 8; ++j) {
    const int k = k0 + j;
    v.h[j] = (n < Nsrc && k < Ksrc) ? (__bf16)src[n * rowlen + k] : (__bf16)0.f;
  }
  *dst = v.u;
}

__device__ __forceinline__ void cvt8(const float* __restrict__ src, uint4* __restrict__ dst) {
  F4 a, b; a.v = *(const float4*)src; b.v = *(const float4*)(src + 4);
  V16 v;
#pragma unroll
  for (int j = 0; j < 4; ++j) { v.h[j] = (__bf16)a.f[j]; v.h[4 + j] = (__bf16)b.f[j]; }
  *dst = v.u;
}

__global__ __launch_bounds__(256) void pack_kernel(
    const float* __restrict__ g1w, const float* __restrict__ g2w,
    const float* __restrict__ e1w, const float* __restrict__ e2w,
    const float* __restrict__ zmw, const float* __restrict__ zvw,
    const float* __restrict__ W,   const float* __restrict__ x,
    uint4* __restrict__ ws4) {
  const int idx = blockIdx.x * 256 + threadIdx.x;
  if (idx >= PACK_THREADS) return;
  const int lane = idx & 63;
  if (idx < B2_OFF) {
    const int f = (idx - B1_OFF) >> 6;
    pack_one(g1w, f >> 1, f & 1, lane, 300, 64, 64, ws4 + idx);
  } else if (idx < E1_OFF) {
    const int f = (idx - B2_OFF) >> 6;
    pack_one(g2w, f / 10, f % 10, lane, 300, 300, 300, ws4 + idx);
  } else if (idx < E2_OFF) {
    const int f = (idx - E1_OFF) >> 6;
    pack_one(e1w, f >> 4, f & 15, lane, 300, 512, 512, ws4 + idx);
  } else if (idx < ZMP_OFF) {
    const int f = (idx - E2_OFF) >> 6;
    pack_one(e2w, f / 10, f % 10, lane, 300, 300, 300, ws4 + idx);
  } else if (idx < ZVP_OFF) {
    const int f = (idx - ZMP_OFF) >> 6;
    pack_one(zmw, f / 10, f % 10, lane, 64, 300, 300, ws4 + idx);
  } else if (idx < FRAG_TOTAL) {
    const int f = (idx - ZVP_OFF) >> 6;
    pack_one(zvw, f / 10, f % 10, lane, 64, 300, 300, ws4 + idx);
  } else if (idx < FRAG_TOTAL + 4096) {
    const int i = idx - FRAG_TOTAL;
    cvt8(W + i * 8, ws4 + WB4 + i);
  } else {
    const int i = idx - FRAG_TOTAL - 4096;
    cvt8(x + i * 8, ws4 + XB4 + i);
  }
}

// enc1: 320 WGs x 256 thr (4 waves, split-K) — R6 verbatim.
__global__ __launch_bounds__(256) void enc1_kernel(
    const uint4* __restrict__ xb, const uint4* __restrict__ e1p,
    const float* __restrict__ e1b, u16* __restrict__ h1) {
  __shared__ float red[4 * 320];
  const int wg = blockIdx.x;
  const int rt = wg / 20, nt = wg % 20;
  const int tid = threadIdx.x;
  const int w = tid >> 6, lane = tid & 63, q = lane >> 4, c = lane & 15;
  f32x4 acc = {0.f, 0.f, 0.f, 0.f};
  const int arow = rt * 16 + c;
#pragma unroll
  for (int j = 0; j < 4; ++j) {
    const int s = 4 * w + j;
    V16 a, b;
    a.u = xb[arow * 64 + s * 4 + q];
    b.u = e1p[(nt * 16 + s) * 64 + lane];
    acc = __builtin_amdgcn_mfma_f32_16x16x32_bf16(a.v, b.v, acc, 0, 0, 0);
  }
#pragma unroll
  for (int i = 0; i < 4; ++i) red[w * 320 + lane * 5 + i] = acc[i];
  __syncthreads();
  const int col = nt * 16 + c;
  float t = 0.f;
#pragma unroll
  for (int ww = 0; ww < 4; ++ww) t += red[ww * 320 + lane * 5 + w];
  const float bias = (col < 300) ? e1b[col] : 0.f;
  const int row = rt * 16 + 4 * q + w;
  V16 o; o.h[0] = (col < 300) ? (__bf16)fmaxf(t + bias, 0.f) : (__bf16)0.f;
  h1[row * 320 + col] = o.s[0];
}

// enc2: 320 WGs x 320 thr (5 waves, split-K) — R6 verbatim.
__global__ __launch_bounds__(320) void enc2_kernel(
    const uint4* __restrict__ h1, const uint4* __restrict__ e2p,
    const float* __restrict__ e2b, u16* __restrict__ h2) {
  __shared__ float red[5 * 320];
  const int wg = blockIdx.x;
  const int rt = wg / 20, nt = wg % 20;
  const int tid = threadIdx.x;
  const int w = tid >> 6, lane = tid & 63, q = lane >> 4, c = lane & 15;
  f32x4 acc = {0.f, 0.f, 0.f, 0.f};
  const int arow = rt * 16 + c;
#pragma unroll
  for (int j = 0; j < 2; ++j) {
    const int s = 2 * w + j;
    V16 a, b;
    a.u = h1[arow * 40 + s * 4 + q];
    b.u = e2p[(nt * 10 + s) * 64 + lane];
    acc = __builtin_amdgcn_mfma_f32_16x16x32_bf16(a.v, b.v, acc, 0, 0, 0);
  }
#pragma unroll
  for (int i = 0; i < 4; ++i) red[w * 320 + lane * 5 + i] = acc[i];
  __syncthreads();
  if (w < 4) {
    const int col = nt * 16 + c;
    float t = 0.f;
#pragma unroll
    for (int ww = 0; ww < 5; ++ww) t += red[ww * 320 + lane * 5 + w];
    const float bias = (col < 300) ? e2b[col] : 0.f;
    const int row = rt * 16 + 4 * q + w;
    V16 o; o.h[0] = (col < 300) ? (__bf16)fmaxf(t + bias, 0.f) : (__bf16)0.f;
    h2[row * 320 + col] = o.s[0];
  }
}

// heads: 64 WGs x 320 thr (5 waves, split-K) — R6 verbatim.
__global__ __launch_bounds__(320) void ench_kernel(
    const uint4* __restrict__ h2, const float* __restrict__ eps,
    const uint4* __restrict__ zmp, const float* __restrict__ zmb,
    const uint4* __restrict__ zvp, const float* __restrict__ zvb,
    float* __restrict__ out) {
  __shared__ float redm[5 * 320];
  __shared__ float redv[5 * 320];
  const int wg = blockIdx.x;
  const int rt = wg >> 2, t = wg & 3;
  const int tid = threadIdx.x;
  const int w = tid >> 6, lane = tid & 63, q = lane >> 4, c = lane & 15;
  f32x4 am = {0.f, 0.f, 0.f, 0.f}, av = {0.f, 0.f, 0.f, 0.f};
  const int arow = rt * 16 + c;
#pragma unroll
  for (int j = 0; j < 2; ++j) {
    const int s = 2 * w + j;
    V16 a, bm, bv;
    a.u = h2[arow * 40 + s * 4 + q];
    bm.u = zmp[(t * 10 + s) * 64 + lane];
    bv.u = zvp[(t * 10 + s) * 64 + lane];
    am = __builtin_amdgcn_mfma_f32_16x16x32_bf16(a.v, bm.v, am, 0, 0, 0);
    av = __builtin_amdgcn_mfma_f32_16x16x32_bf16(a.v, bv.v, av, 0, 0, 0);
  }
#pragma unroll
  for (int i = 0; i < 4; ++i) {
    redm[w * 320 + lane * 5 + i] = am[i];
    redv[w * 320 + lane * 5 + i] = av[i];
  }
  __syncthreads();
  if (w < 4) {
    const int col = t * 16 + c;
    float tm = 0.f, tv = 0.f;
#pragma unroll
    for (int ww = 0; ww < 5; ++ww) {
      tm += redm[ww * 320 + lane * 5 + w];
      tv += redv[ww * 320 + lane * 5 + w];
    }
    const float zm = tm + zmb[col];
    const float zlv = tv + zvb[col];
    const int gi = (rt * 16 + 4 * q + w) * 64 + col;
    out[ZM_OFF + gi] = zm;
    out[ZLV_OFF + gi] = zlv;
    out[Z_OFF + gi] = zm + eps[gi] * expf(0.5f * zlv);
  }
}

// ---------------------------------------------------------------------------
// Fused decoder: 2048 WGs x 320 thr. R0's per-tile body VERBATIM, wrapped in
// a 2-iteration bi-loop at fixed d0: block (bi0, ds) does bi=2*bi0, 2*bi0+1.
// Second tile's Wb (same d0), hw (same addresses — bi-independent), b2p hit
// L1/L2 warm; per-block fixed costs amortize x2; LDS/VGPR unchanged.
// Block ordering keeps R0's bi-major/ds-minor (proven XCD-local in R10).
// ---------------------------------------------------------------------------
__global__ __launch_bounds__(320, 4) void dec_kernel(
    const float* __restrict__ z,     // [256][64] (fp32, in d_out)
    const uint4* __restrict__ Wb,    // bf16 [512][64]
    const uint4* __restrict__ b1p,
    const uint4* __restrict__ b2p,
    const float* __restrict__ g2b,
    const float* __restrict__ hw,    // [512][300] fp32
    const float* __restrict__ hb,
    float* __restrict__ xout) {
  __shared__ u16 g1s[32 * 328];     // 20,992 B (reused as xred after barrier)
  float* xredf = (float*)g1s;

  const int wg = blockIdx.x;        // 0..2047
  const int ds = wg & 15;
  const int bi0 = wg >> 4;
  const int d0 = ds << 5;
  const int tid = threadIdx.x;
  const int u = tid >> 6;
  const int lane = tid & 63;
  const int q = lane >> 4;
  const int c = lane & 15;

  for (int it = 0; it < 2; ++it) {
    const int bi = bi0 * 2 + it;
    const int r0 = (bi << 9) | d0;
    const float* zrow = z + bi * 64;

    // ---- stage 2 (R0 verbatim) ----
    bf16x8 bz[4][2];
#pragma unroll
    for (int kf = 0; kf < 2; ++kf) {
      F4 z0, z1;
      z0.v = *(const float4*)(zrow + kf * 32 + q * 8);
      z1.v = *(const float4*)(zrow + kf * 32 + q * 8 + 4);
#pragma unroll
      for (int tt = 0; tt < 4; ++tt) {
        V16 r; r.u = b1p[((4 * u + tt) * 2 + kf) * 64 + lane];
        V16 m;
#pragma unroll
        for (int j = 0; j < 4; ++j) {
          m.h[j]     = (__bf16)(bf2f(r.s[j])     * z0.f[j]);
          m.h[4 + j] = (__bf16)(bf2f(r.s[4 + j]) * z1.f[j]);
        }
        bz[tt][kf] = m.v;
      }
    }
#pragma unroll
    for (int rt = 0; rt < 2; ++rt) {
      const int rowA = rt * 16 + c;
      V16 af0, af1;
      af0.u = Wb[(d0 + rowA) * 8 + q];
      af1.u = Wb[(d0 + rowA) * 8 + 4 + q];
      f32x4 acc[4];
#pragma unroll
      for (int tt = 0; tt < 4; ++tt) acc[tt] = {0.f, 0.f, 0.f, 0.f};
#pragma unroll
      for (int tt = 0; tt < 4; ++tt) {
        acc[tt] = __builtin_amdgcn_mfma_f32_16x16x32_bf16(af0.v, bz[tt][0], acc[tt], 0, 0, 0);
        acc[tt] = __builtin_amdgcn_mfma_f32_16x16x32_bf16(af1.v, bz[tt][1], acc[tt], 0, 0, 0);
      }
      const int rwb = rt * 16 + 4 * q;
#pragma unroll
      for (int tt = 0; tt < 4; ++tt) {
        const int colb = (4 * u + tt) * 16 + c;
#pragma unroll
        for (int i = 0; i < 4; ++i) {
          V16 t; t.h[0] = (__bf16)fmaxf(acc[tt][i], 0.f);
          g1s[(rwb + i) * 328 + colb] = t.s[0];
        }
      }
    }
    __syncthreads();

    // ---- stage 3 (R0 verbatim) ----
    f32x4 a3[4][2];
#pragma unroll
    for (int tt = 0; tt < 4; ++tt)
#pragma unroll
      for (int rt = 0; rt < 2; ++rt) a3[tt][rt] = {0.f, 0.f, 0.f, 0.f};
    for (int s = 0; s < 10; ++s) {
      V16 b[4];
#pragma unroll
      for (int tt = 0; tt < 4; ++tt) b[tt].u = b2p[((4 * u + tt) * 10 + s) * 64 + lane];
#pragma unroll
      for (int rt = 0; rt < 2; ++rt) {
        V16 a; a.u = *(const uint4*)&g1s[(rt * 16 + c) * 328 + s * 32 + q * 8];
#pragma unroll
        for (int tt = 0; tt < 4; ++tt)
          a3[tt][rt] = __builtin_amdgcn_mfma_f32_16x16x32_bf16(a.v, b[tt].v, a3[tt][rt], 0, 0, 0);
      }
    }
    float xacc[2][4];
#pragma unroll
    for (int rt = 0; rt < 2; ++rt)
#pragma unroll
      for (int i = 0; i < 4; ++i) xacc[rt][i] = 0.f;
#pragma unroll
    for (int tt = 0; tt < 4; ++tt) {
      const int col = (4 * u + tt) * 16 + c;
      const bool inb = (col < 300);
      const float bias = inb ? g2b[col] : 0.f;
#pragma unroll
      for (int rt = 0; rt < 2; ++rt)
#pragma unroll
        for (int i = 0; i < 4; ++i) {
          const float g2v = fmaxf(a3[tt][rt][i] + bias, 0.f);
          const float h = inb ? hw[(d0 + rt * 16 + 4 * q + i) * 300 + col] : 0.f;
          xacc[rt][i] += g2v * h;
        }
    }
#pragma unroll
    for (int rt = 0; rt < 2; ++rt)
#pragma unroll
      for (int i = 0; i < 4; ++i) {
        float t = xacc[rt][i];
        t += __shfl_xor(t, 1);
        t += __shfl_xor(t, 2);
        t += __shfl_xor(t, 4);
        t += __shfl_xor(t, 8);
        xacc[rt][i] = t;
      }
    __syncthreads();   // g1s reads done; safe to alias as xred
    if (c < 4) {
#pragma unroll
      for (int rt = 0; rt < 2; ++rt) {
        float t = xacc[rt][0];
        t = (c == 1) ? xacc[rt][1] : t;
        t = (c == 2) ? xacc[rt][2] : t;
        t = (c == 3) ? xacc[rt][3] : t;
        xredf[u * 32 + rt * 16 + 4 * q + c] = t;
      }
    }
    __syncthreads();
    if (tid < 32) {
      float t = hb[d0 + tid];
#pragma unroll
      for (int uu = 0; uu < 5; ++uu) t += xredf[uu * 32 + tid];
      xout[r0 + tid] = t;
    }
    __syncthreads();   // xred reads done before next tile overwrites g1s
  }
}

extern "C" void kernel_launch(void* const* d_in, const int* in_sizes, int n_in,
                              void* d_out, int out_size, void* d_ws, size_t ws_size,
                              hipStream_t stream) {
  const float* x   = (const float*)d_in[0];
  const float* eps = (const float*)d_in[1];
  const float* W   = (const float*)d_in[2];
  const float* e1w = (const float*)d_in[3];
  const float* e1b = (const float*)d_in[4];
  const float* e2w = (const float*)d_in[5];
  const float* e2b = (const float*)d_in[6];
  const float* zmw = (const float*)d_in[7];
  const float* zmb = (const float*)d_in[8];
  const float* zvw = (const float*)d_in[9];
  const float* zvb = (const float*)d_in[10];
  const float* g1w = (const float*)d_in[11];
  const float* g2w = (const float*)d_in[12];
  const float* g2b = (const float*)d_in[13];
  const float* hw  = (const float*)d_in[14];
  const float* hb  = (const float*)d_in[15];
  float* out = (float*)d_out;
  uint4* ws4 = (uint4*)d_ws;

  pack_kernel<<<(PACK_THREADS + 255) / 256, 256, 0, stream>>>(
      g1w, g2w, e1w, e2w, zmw, zvw, W, x, ws4);
  enc1_kernel<<<320, 256, 0, stream>>>(ws4 + XB4, ws4 + E1_OFF, e1b, (u16*)(ws4 + H1_4));
  enc2_kernel<<<320, 320, 0, stream>>>(ws4 + H1_4, ws4 + E2_OFF, e2b, (u16*)(ws4 + H2_4));
  ench_kernel<<<64, 320, 0, stream>>>(ws4 + H2_4, eps,
                                      ws4 + ZMP_OFF, zmb, ws4 + ZVP_OFF, zvb, out);
  dec_kernel<<<2048, 320, 0, stream>>>(out + Z_OFF, ws4 + WB4,
                                       ws4 + B1_OFF, ws4 + B2_OFF,
                                       g2b, hw, hb, out);
}

// Round 12
// 162.270 us; speedup vs baseline: 2.8789x; 2.8789x over previous
//
#include <hip/hip_runtime.h>

typedef unsigned short u16;
typedef unsigned int u32;

typedef __bf16 bf16x8 __attribute__((ext_vector_type(8)));
typedef float f32x4 __attribute__((ext_vector_type(4)));

union V16 { uint4 u; bf16x8 v; u16 s[8]; __bf16 h[8]; };
union F4  { float4 v; float f[4]; };

__device__ __forceinline__ float bf2f(u16 a) {
  union { u32 u; float f; } c; c.u = ((u32)a) << 16; return c.f;
}

#define Z_OFF   131072
#define ZM_OFF  147456
#define ZLV_OFF 163840

// ws layout in uint4 units (R0 layout, verbatim).
#define B1_OFF 0        // gen1_w: t<20, s<2
#define B2_OFF 2560     // gen2_w: t<20, s<10
#define E1_OFF 15360    // enc1_w: t<20, s<16
#define E2_OFF 35840    // enc2_w: t<20, s<10
#define ZMP_OFF 48640   // zm_w: t<4, s<10
#define ZVP_OFF 51200   // zv_w: t<4, s<10
#define FRAG_TOTAL 53760
#define WB4  53760      // W bf16 [512][64]     : 4096 uint4
#define XB4  57856      // x bf16 [256][512]    : 16384 uint4
#define H1_4 74240      // h1 bf16 [256][320]   : 10240 uint4
#define H2_4 84480      // h2 bf16 [256][320]   : 10240 uint4
#define PACK_THREADS (FRAG_TOTAL + 4096 + 16384)   // 74240

__device__ __forceinline__ void pack_one(const float* __restrict__ src,
                                         int t, int s, int lane,
                                         int Nsrc, int Ksrc, int rowlen,
                                         uint4* __restrict__ dst) {
  const int n = t * 16 + (lane & 15);
  const int k0 = s * 32 + ((lane >> 4) << 3);
  V16 v;
#pragma unroll
  for (int j = 0; j < 8; ++j) {
    const int k = k0 + j;
    v.h[j] = (n < Nsrc && k < Ksrc) ? (__bf16)src[n * rowlen + k] : (__bf16)0.f;
  }
  *dst = v.u;
}

__device__ __forceinline__ void cvt8(const float* __restrict__ src, uint4* __restrict__ dst) {
  F4 a, b; a.v = *(const float4*)src; b.v = *(const float4*)(src + 4);
  V16 v;
#pragma unroll
  for (int j = 0; j < 4; ++j) { v.h[j] = (__bf16)a.f[j]; v.h[4 + j] = (__bf16)b.f[j]; }
  *dst = v.u;
}

__global__ __launch_bounds__(256) void pack_kernel(
    const float* __restrict__ g1w, const float* __restrict__ g2w,
    const float* __restrict__ e1w, const float* __restrict__ e2w,
    const float* __restrict__ zmw, const float* __restrict__ zvw,
    const float* __restrict__ W,   const float* __restrict__ x,
    uint4* __restrict__ ws4) {
  const int idx = blockIdx.x * 256 + threadIdx.x;
  if (idx >= PACK_THREADS) return;
  const int lane = idx & 63;
  if (idx < B2_OFF) {
    const int f = (idx - B1_OFF) >> 6;
    pack_one(g1w, f >> 1, f & 1, lane, 300, 64, 64, ws4 + idx);
  } else if (idx < E1_OFF) {
    const int f = (idx - B2_OFF) >> 6;
    pack_one(g2w, f / 10, f % 10, lane, 300, 300, 300, ws4 + idx);
  } else if (idx < E2_OFF) {
    const int f = (idx - E1_OFF) >> 6;
    pack_one(e1w, f >> 4, f & 15, lane, 300, 512, 512, ws4 + idx);
  } else if (idx < ZMP_OFF) {
    const int f = (idx - E2_OFF) >> 6;
    pack_one(e2w, f / 10, f % 10, lane, 300, 300, 300, ws4 + idx);
  } else if (idx < ZVP_OFF) {
    const int f = (idx - ZMP_OFF) >> 6;
    pack_one(zmw, f / 10, f % 10, lane, 64, 300, 300, ws4 + idx);
  } else if (idx < FRAG_TOTAL) {
    const int f = (idx - ZVP_OFF) >> 6;
    pack_one(zvw, f / 10, f % 10, lane, 64, 300, 300, ws4 + idx);
  } else if (idx < FRAG_TOTAL + 4096) {
    const int i = idx - FRAG_TOTAL;
    cvt8(W + i * 8, ws4 + WB4 + i);
  } else {
    const int i = idx - FRAG_TOTAL - 4096;
    cvt8(x + i * 8, ws4 + XB4 + i);
  }
}

// enc1: 320 WGs x 256 thr (4 waves, split-K) — R6 verbatim.
__global__ __launch_bounds__(256) void enc1_kernel(
    const uint4* __restrict__ xb, const uint4* __restrict__ e1p,
    const float* __restrict__ e1b, u16* __restrict__ h1) {
  __shared__ float red[4 * 320];
  const int wg = blockIdx.x;
  const int rt = wg / 20, nt = wg % 20;
  const int tid = threadIdx.x;
  const int w = tid >> 6, lane = tid & 63, q = lane >> 4, c = lane & 15;
  f32x4 acc = {0.f, 0.f, 0.f, 0.f};
  const int arow = rt * 16 + c;
#pragma unroll
  for (int j = 0; j < 4; ++j) {
    const int s = 4 * w + j;
    V16 a, b;
    a.u = xb[arow * 64 + s * 4 + q];
    b.u = e1p[(nt * 16 + s) * 64 + lane];
    acc = __builtin_amdgcn_mfma_f32_16x16x32_bf16(a.v, b.v, acc, 0, 0, 0);
  }
#pragma unroll
  for (int i = 0; i < 4; ++i) red[w * 320 + lane * 5 + i] = acc[i];
  __syncthreads();
  const int col = nt * 16 + c;
  float t = 0.f;
#pragma unroll
  for (int ww = 0; ww < 4; ++ww) t += red[ww * 320 + lane * 5 + w];
  const float bias = (col < 300) ? e1b[col] : 0.f;
  const int row = rt * 16 + 4 * q + w;
  V16 o; o.h[0] = (col < 300) ? (__bf16)fmaxf(t + bias, 0.f) : (__bf16)0.f;
  h1[row * 320 + col] = o.s[0];
}

// enc2: 320 WGs x 320 thr (5 waves, split-K) — R6 verbatim.
__global__ __launch_bounds__(320) void enc2_kernel(
    const uint4* __restrict__ h1, const uint4* __restrict__ e2p,
    const float* __restrict__ e2b, u16* __restrict__ h2) {
  __shared__ float red[5 * 320];
  const int wg = blockIdx.x;
  const int rt = wg / 20, nt = wg % 20;
  const int tid = threadIdx.x;
  const int w = tid >> 6, lane = tid & 63, q = lane >> 4, c = lane & 15;
  f32x4 acc = {0.f, 0.f, 0.f, 0.f};
  const int arow = rt * 16 + c;
#pragma unroll
  for (int j = 0; j < 2; ++j) {
    const int s = 2 * w + j;
    V16 a, b;
    a.u = h1[arow * 40 + s * 4 + q];
    b.u = e2p[(nt * 10 + s) * 64 + lane];
    acc = __builtin_amdgcn_mfma_f32_16x16x32_bf16(a.v, b.v, acc, 0, 0, 0);
  }
#pragma unroll
  for (int i = 0; i < 4; ++i) red[w * 320 + lane * 5 + i] = acc[i];
  __syncthreads();
  if (w < 4) {
    const int col = nt * 16 + c;
    float t = 0.f;
#pragma unroll
    for (int ww = 0; ww < 5; ++ww) t += red[ww * 320 + lane * 5 + w];
    const float bias = (col < 300) ? e2b[col] : 0.f;
    const int row = rt * 16 + 4 * q + w;
    V16 o; o.h[0] = (col < 300) ? (__bf16)fmaxf(t + bias, 0.f) : (__bf16)0.f;
    h2[row * 320 + col] = o.s[0];
  }
}

// heads: 64 WGs x 320 thr (5 waves, split-K) — R6 verbatim.
__global__ __launch_bounds__(320) void ench_kernel(
    const uint4* __restrict__ h2, const float* __restrict__ eps,
    const uint4* __restrict__ zmp, const float* __restrict__ zmb,
    const uint4* __restrict__ zvp, const float* __restrict__ zvb,
    float* __restrict__ out) {
  __shared__ float redm[5 * 320];
  __shared__ float redv[5 * 320];
  const int wg = blockIdx.x;
  const int rt = wg >> 2, t = wg & 3;
  const int tid = threadIdx.x;
  const int w = tid >> 6, lane = tid & 63, q = lane >> 4, c = lane & 15;
  f32x4 am = {0.f, 0.f, 0.f, 0.f}, av = {0.f, 0.f, 0.f, 0.f};
  const int arow = rt * 16 + c;
#pragma unroll
  for (int j = 0; j < 2; ++j) {
    const int s = 2 * w + j;
    V16 a, bm, bv;
    a.u = h2[arow * 40 + s * 4 + q];
    bm.u = zmp[(t * 10 + s) * 64 + lane];
    bv.u = zvp[(t * 10 + s) * 64 + lane];
    am = __builtin_amdgcn_mfma_f32_16x16x32_bf16(a.v, bm.v, am, 0, 0, 0);
    av = __builtin_amdgcn_mfma_f32_16x16x32_bf16(a.v, bv.v, av, 0, 0, 0);
  }
#pragma unroll
  for (int i = 0; i < 4; ++i) {
    redm[w * 320 + lane * 5 + i] = am[i];
    redv[w * 320 + lane * 5 + i] = av[i];
  }
  __syncthreads();
  if (w < 4) {
    const int col = t * 16 + c;
    float tm = 0.f, tv = 0.f;
#pragma unroll
    for (int ww = 0; ww < 5; ++ww) {
      tm += redm[ww * 320 + lane * 5 + w];
      tv += redv[ww * 320 + lane * 5 + w];
    }
    const float zm = tm + zmb[col];
    const float zlv = tv + zvb[col];
    const int gi = (rt * 16 + 4 * q + w) * 64 + col;
    out[ZM_OFF + gi] = zm;
    out[ZLV_OFF + gi] = zlv;
    out[Z_OFF + gi] = zm + eps[gi] * expf(0.5f * zlv);
  }
}

// ---------------------------------------------------------------------------
// Fused decoder (R0 verbatim — the verified 79.6us schedule, VGPR=48).
// 4096 WGs x 320 thr (5 waves). 32 rows/WG. Seven perturbations (64-row,
// 10-wave, coop, producer-consumer, preload+pipeline, d-major, bi-loop)
// all regressed: this body sits at the register-allocation edge; any added
// live range or enclosing loop costs occupancy or spills.
// ---------------------------------------------------------------------------
__global__ __launch_bounds__(320, 4) void dec_kernel(
    const float* __restrict__ z,     // [256][64] (fp32, in d_out)
    const uint4* __restrict__ Wb,    // bf16 [512][64]
    const uint4* __restrict__ b1p,
    const uint4* __restrict__ b2p,
    const float* __restrict__ g2b,
    const float* __restrict__ hw,    // [512][300] fp32
    const float* __restrict__ hb,
    float* __restrict__ xout) {
  __shared__ u16 g1s[32 * 328];     // 20,992 B (reused as xred after barrier)
  float* xredf = (float*)g1s;

  const int wg = blockIdx.x;
  const int r0 = wg << 5;
  const int bi = wg >> 4;
  const int d0 = r0 & 511;
  const int tid = threadIdx.x;
  const int u = tid >> 6;
  const int lane = tid & 63;
  const int q = lane >> 4;
  const int c = lane & 15;

  const float* zrow = z + bi * 64;

  // ---- stage 2 ----
  bf16x8 bz[4][2];
#pragma unroll
  for (int kf = 0; kf < 2; ++kf) {
    F4 z0, z1;
    z0.v = *(const float4*)(zrow + kf * 32 + q * 8);
    z1.v = *(const float4*)(zrow + kf * 32 + q * 8 + 4);
#pragma unroll
    for (int tt = 0; tt < 4; ++tt) {
      V16 r; r.u = b1p[((4 * u + tt) * 2 + kf) * 64 + lane];
      V16 m;
#pragma unroll
      for (int j = 0; j < 4; ++j) {
        m.h[j]     = (__bf16)(bf2f(r.s[j])     * z0.f[j]);
        m.h[4 + j] = (__bf16)(bf2f(r.s[4 + j]) * z1.f[j]);
      }
      bz[tt][kf] = m.v;
    }
  }
#pragma unroll
  for (int rt = 0; rt < 2; ++rt) {
    const int rowA = rt * 16 + c;
    V16 af0, af1;
    af0.u = Wb[(d0 + rowA) * 8 + q];
    af1.u = Wb[(d0 + rowA) * 8 + 4 + q];
    f32x4 acc[4];
#pragma unroll
    for (int tt = 0; tt < 4; ++tt) acc[tt] = {0.f, 0.f, 0.f, 0.f};
#pragma unroll
    for (int tt = 0; tt < 4; ++tt) {
      acc[tt] = __builtin_amdgcn_mfma_f32_16x16x32_bf16(af0.v, bz[tt][0], acc[tt], 0, 0, 0);
      acc[tt] = __builtin_amdgcn_mfma_f32_16x16x32_bf16(af1.v, bz[tt][1], acc[tt], 0, 0, 0);
    }
    const int rwb = rt * 16 + 4 * q;
#pragma unroll
    for (int tt = 0; tt < 4; ++tt) {
      const int colb = (4 * u + tt) * 16 + c;
#pragma unroll
      for (int i = 0; i < 4; ++i) {
        V16 t; t.h[0] = (__bf16)fmaxf(acc[tt][i], 0.f);
        g1s[(rwb + i) * 328 + colb] = t.s[0];
      }
    }
  }
  __syncthreads();

  // ---- stage 3 ----
  f32x4 a3[4][2];
#pragma unroll
  for (int tt = 0; tt < 4; ++tt)
#pragma unroll
    for (int rt = 0; rt < 2; ++rt) a3[tt][rt] = {0.f, 0.f, 0.f, 0.f};
  for (int s = 0; s < 10; ++s) {
    V16 b[4];
#pragma unroll
    for (int tt = 0; tt < 4; ++tt) b[tt].u = b2p[((4 * u + tt) * 10 + s) * 64 + lane];
#pragma unroll
    for (int rt = 0; rt < 2; ++rt) {
      V16 a; a.u = *(const uint4*)&g1s[(rt * 16 + c) * 328 + s * 32 + q * 8];
#pragma unroll
      for (int tt = 0; tt < 4; ++tt)
        a3[tt][rt] = __builtin_amdgcn_mfma_f32_16x16x32_bf16(a.v, b[tt].v, a3[tt][rt], 0, 0, 0);
    }
  }
  float xacc[2][4];
#pragma unroll
  for (int rt = 0; rt < 2; ++rt)
#pragma unroll
    for (int i = 0; i < 4; ++i) xacc[rt][i] = 0.f;
#pragma unroll
  for (int tt = 0; tt < 4; ++tt) {
    const int col = (4 * u + tt) * 16 + c;
    const bool inb = (col < 300);
    const float bias = inb ? g2b[col] : 0.f;
#pragma unroll
    for (int rt = 0; rt < 2; ++rt)
#pragma unroll
      for (int i = 0; i < 4; ++i) {
        const float g2v = fmaxf(a3[tt][rt][i] + bias, 0.f);
        const float h = inb ? hw[(d0 + rt * 16 + 4 * q + i) * 300 + col] : 0.f;
        xacc[rt][i] += g2v * h;
      }
  }
#pragma unroll
  for (int rt = 0; rt < 2; ++rt)
#pragma unroll
    for (int i = 0; i < 4; ++i) {
      float t = xacc[rt][i];
      t += __shfl_xor(t, 1);
      t += __shfl_xor(t, 2);
      t += __shfl_xor(t, 4);
      t += __shfl_xor(t, 8);
      xacc[rt][i] = t;
    }
  __syncthreads();
  if (c < 4) {
#pragma unroll
    for (int rt = 0; rt < 2; ++rt) {
      float t = xacc[rt][0];
      t = (c == 1) ? xacc[rt][1] : t;
      t = (c == 2) ? xacc[rt][2] : t;
      t = (c == 3) ? xacc[rt][3] : t;
      xredf[u * 32 + rt * 16 + 4 * q + c] = t;
    }
  }
  __syncthreads();
  if (tid < 32) {
    float t = hb[d0 + tid];
#pragma unroll
    for (int uu = 0; uu < 5; ++uu) t += xredf[uu * 32 + tid];
    xout[r0 + tid] = t;
  }
}

extern "C" void kernel_launch(void* const* d_in, const int* in_sizes, int n_in,
                              void* d_out, int out_size, void* d_ws, size_t ws_size,
                              hipStream_t stream) {
  const float* x   = (const float*)d_in[0];
  const float* eps = (const float*)d_in[1];
  const float* W   = (const float*)d_in[2];
  const float* e1w = (const float*)d_in[3];
  const float* e1b = (const float*)d_in[4];
  const float* e2w = (const float*)d_in[5];
  const float* e2b = (const float*)d_in[6];
  const float* zmw = (const float*)d_in[7];
  const float* zmb = (const float*)d_in[8];
  const float* zvw = (const float*)d_in[9];
  const float* zvb = (const float*)d_in[10];
  const float* g1w = (const float*)d_in[11];
  const float* g2w = (const float*)d_in[12];
  const float* g2b = (const float*)d_in[13];
  const float* hw  = (const float*)d_in[14];
  const float* hb  = (const float*)d_in[15];
  float* out = (float*)d_out;
  uint4* ws4 = (uint4*)d_ws;

  pack_kernel<<<(PACK_THREADS + 255) / 256, 256, 0, stream>>>(
      g1w, g2w, e1w, e2w, zmw, zvw, W, x, ws4);
  enc1_kernel<<<320, 256, 0, stream>>>(ws4 + XB4, ws4 + E1_OFF, e1b, (u16*)(ws4 + H1_4));
  enc2_kernel<<<320, 320, 0, stream>>>(ws4 + H1_4, ws4 + E2_OFF, e2b, (u16*)(ws4 + H2_4));
  ench_kernel<<<64, 320, 0, stream>>>(ws4 + H2_4, eps,
                                      ws4 + ZMP_OFF, zmb, ws4 + ZVP_OFF, zvb, out);
  dec_kernel<<<4096, 320, 0, stream>>>(out + Z_OFF, ws4 + WB4,
                                       ws4 + B1_OFF, ws4 + B2_OFF,
                                       g2b, hw, hb, out);
}